// Round 13
// baseline (144.084 us; speedup 1.0000x reference)
//
#include <hip/hip_runtime.h>
#include <hip/hip_bf16.h>

#define N_PTS 4096
#define M_PTS 16384
#define CIN   256
#define CSK   128
#define KDIM  384   // CIN + CSK
#define HDIM  256
#define NSHARD 32
#define SHPTS (N_PTS / NSHARD)   // 128

typedef unsigned int  u32;
typedef unsigned short u16;
typedef unsigned long long u64;
typedef __attribute__((ext_vector_type(8))) short bf16x8;
typedef __attribute__((ext_vector_type(4))) float f32x4;

__device__ __forceinline__ u16 f2bf(float f) {
    union { float f; u32 i; } w; w.f = f;
    u32 x = w.i;
    u32 r = x + 0x7fffu + ((x >> 16) & 1u);   // RTNE
    return (u16)(r >> 16);
}

// strict "better" with lower-index tie-break (stable-sort semantics)
__device__ __forceinline__ bool ltk(float s, int p, float t, int i) {
    return (s < t) || (s == t && p < i);
}
__device__ __forceinline__ void ins3(float s, int p,
                                     float& t0, float& t1, float& t2,
                                     int& i0, int& i1, int& i2) {
    if (ltk(s, p, t2, i2)) {
        if (ltk(s, p, t1, i1)) {
            t2 = t1; i2 = i1;
            if (ltk(s, p, t0, i0)) { t1 = t0; i1 = i0; t0 = s; i0 = p; }
            else                   { t1 = s;  i1 = p; }
        } else { t2 = s; i2 = p; }
    }
}

// value-only sorted-top3 insert: EXACT (min/med3 are rounding-free), 3 VALU.
#define VINS(s, t0, t1, t2)                                               \
    {                                                                     \
        float _o0 = t0, _o1 = t1;                                         \
        t0 = fminf(_o0, (s));                                             \
        t1 = __builtin_amdgcn_fmed3f(_o0, t1, (s));                       \
        t2 = __builtin_amdgcn_fmed3f(_o1, t2, (s));                       \
    }

// ---------------------------------------------------------------------------
// Kernel 0: W1 [384][256] f32 -> W1T [256][384] bf16 (transposed, RTNE)
// ---------------------------------------------------------------------------
__global__ __launch_bounds__(384) void prep_w1t(
    const float* __restrict__ W1, u16* __restrict__ W1T)
{
    const int n = blockIdx.x;       // 256 blocks
    const int k = threadIdx.x;      // 384 threads
    W1T[(size_t)n * KDIM + k] = f2bf(W1[(size_t)k * HDIM + n]);
}

// ---------------------------------------------------------------------------
// Kernel 1: VALUE-ONLY sharded 3-NN scan (round-12 proven, unchanged).
// candV[sh*M + m] = (t0,t1,t2,0)  (3 smallest d^2 values in shard, exact)
// ---------------------------------------------------------------------------
__global__ __launch_bounds__(256, 8) void knn_scanV(
    const float* __restrict__ pos,
    const float* __restrict__ pos_skip,
    float4* __restrict__ candV)
{
    __shared__ float4 spts[SHPTS];     // 128 x 16B = 2 KB
    const int tid = threadIdx.x;
    const int sh = blockIdx.y;
    const int pbase = sh * SHPTS;
    const int m0 = blockIdx.x * 512 + tid;
    const int m1 = m0 + 256;

    if (tid < SHPTS) {
        const int i = pbase + tid;
        float px = pos[3 * i], py = pos[3 * i + 1], pz = pos[3 * i + 2];
        float pn = __fadd_rn(__fadd_rn(__fmul_rn(px, px), __fmul_rn(py, py)),
                             __fmul_rn(pz, pz));
        spts[tid] = make_float4(px, py, pz, pn);
    }

    const float qx0 = pos_skip[3 * m0];
    const float qy0 = pos_skip[3 * m0 + 1];
    const float qz0 = pos_skip[3 * m0 + 2];
    const float qn0 = __fadd_rn(__fadd_rn(__fmul_rn(qx0, qx0), __fmul_rn(qy0, qy0)),
                                __fmul_rn(qz0, qz0));
    const float qx1 = pos_skip[3 * m1];
    const float qy1 = pos_skip[3 * m1 + 1];
    const float qz1 = pos_skip[3 * m1 + 2];
    const float qn1 = __fadd_rn(__fadd_rn(__fmul_rn(qx1, qx1), __fmul_rn(qy1, qy1)),
                                __fmul_rn(qz1, qz1));
    __syncthreads();

    float e0[2][2], e1[2][2], e2[2][2];
    #pragma unroll
    for (int q = 0; q < 2; ++q)
        #pragma unroll
        for (int c = 0; c < 2; ++c) {
            e0[q][c] = 3.4e38f; e1[q][c] = 3.4e38f; e2[q][c] = 3.4e38f;
        }

    #pragma unroll 8
    for (int j = 0; j < SHPTS; ++j) {
        float4 v = spts[j];            // wave-uniform broadcast read
        const int c = j & 1;
        {
            float b = __fmaf_rn(qz0, v.z, __fmaf_rn(qy0, v.y, __fmul_rn(qx0, v.x)));
            float s = __fadd_rn(__fmaf_rn(-2.0f, b, qn0), v.w);
            VINS(s, e0[0][c], e1[0][c], e2[0][c]);
        }
        {
            float b = __fmaf_rn(qz1, v.z, __fmaf_rn(qy1, v.y, __fmul_rn(qx1, v.x)));
            float s = __fadd_rn(__fmaf_rn(-2.0f, b, qn1), v.w);
            VINS(s, e0[1][c], e1[1][c], e2[1][c]);
        }
    }

    #pragma unroll
    for (int q = 0; q < 2; ++q) {
        VINS(e0[q][1], e0[q][0], e1[q][0], e2[q][0]);
        VINS(e1[q][1], e0[q][0], e1[q][0], e2[q][0]);
        VINS(e2[q][1], e0[q][0], e1[q][0], e2[q][0]);
    }

    candV[(size_t)sh * M_PTS + m0] = make_float4(e0[0][0], e1[0][0], e2[0][0], 0.f);
    candV[(size_t)sh * M_PTS + m1] = make_float4(e0[1][0], e1[1][0], e2[1][0], 0.f);
}

// ---------------------------------------------------------------------------
// Kernel 2: THREAD-per-query mask build (coalesced candV streaming).
// u2 = exact global 3rd-smallest (VINS over the 96 shard-top3 values);
// mask bit sh set iff shard-min <= u2 (superset of shards holding top-3;
// at most 3 bits can be set). 64 blocks x 256 threads.
// ---------------------------------------------------------------------------
__global__ __launch_bounds__(256) void knn_mask(
    const float4* __restrict__ candV,
    u32* __restrict__ nbrm)
{
    const int m = blockIdx.x * 256 + threadIdx.x;
    float mn[NSHARD];
    float u0 = 3.4e38f, u1 = 3.4e38f, u2 = 3.4e38f;
    #pragma unroll
    for (int sh = 0; sh < NSHARD; ++sh) {
        float4 cv = candV[(size_t)sh * M_PTS + m];   // coalesced across threads
        mn[sh] = cv.x;
        VINS(cv.x, u0, u1, u2);
        VINS(cv.y, u0, u1, u2);
        VINS(cv.z, u0, u1, u2);
    }
    u32 mask = 0;
    #pragma unroll
    for (int sh = 0; sh < NSHARD; ++sh)
        mask |= (mn[sh] <= u2) ? (1u << sh) : 0u;
    nbrm[m] = mask;
}

// ---------------------------------------------------------------------------
// Kernel 3: WAVE-per-query rescan of qualifying shards (round-12-proven
// components only: accumulate-all ins3 + 64-lane butterfly). mask is wave-
// uniform; <=3 shards, 128 contiguous points each (coalesced loads).
// ---------------------------------------------------------------------------
__global__ __launch_bounds__(256) void knn_rescan(
    const float* __restrict__ pos,
    const float* __restrict__ pos_skip,
    const u32* __restrict__ nbrm,
    float4* __restrict__ nbrw, uint4* __restrict__ nbri)
{
    const int tid  = threadIdx.x;
    const int wave = tid >> 6;
    const int lane = tid & 63;
    const int m = blockIdx.x * 4 + wave;   // 4096 blocks * 4 waves = 16384

    const float qx = pos_skip[3 * m];
    const float qy = pos_skip[3 * m + 1];
    const float qz = pos_skip[3 * m + 2];
    const float qn = __fadd_rn(__fadd_rn(__fmul_rn(qx, qx), __fmul_rn(qy, qy)),
                               __fmul_rn(qz, qz));

    u32 mask = nbrm[m];                     // wave-uniform

    float t0 = 3.4e38f, t1 = 3.4e38f, t2 = 3.4e38f;
    int   i0 = 0x7fffffff, i1 = 0x7fffffff, i2 = 0x7fffffff;

    while (mask) {
        const int sh = __ffs(mask) - 1; mask &= mask - 1;
        const int pb = sh * SHPTS;
        #pragma unroll
        for (int it = 0; it < 2; ++it) {
            const int p = pb + it * 64 + lane;
            float px = pos[3 * p], py = pos[3 * p + 1], pz = pos[3 * p + 2];
            float pn = __fadd_rn(__fadd_rn(__fmul_rn(px, px), __fmul_rn(py, py)),
                                 __fmul_rn(pz, pz));
            float b = __fmaf_rn(qz, pz, __fmaf_rn(qy, py, __fmul_rn(qx, px)));
            float s = __fadd_rn(__fmaf_rn(-2.0f, b, qn), pn);
            ins3(s, p, t0, t1, t2, i0, i1, i2);
        }
    }

    // proven 64-lane butterfly (value,index) merge -> all lanes identical
    #pragma unroll
    for (int off = 1; off < 64; off <<= 1) {
        float o0 = __shfl_xor(t0, off);
        float o1 = __shfl_xor(t1, off);
        float o2 = __shfl_xor(t2, off);
        int   j0 = __shfl_xor(i0, off);
        int   j1 = __shfl_xor(i1, off);
        int   j2 = __shfl_xor(i2, off);
        ins3(o0, j0, t0, t1, t2, i0, i1, i2);
        ins3(o1, j1, t0, t1, t2, i0, i1, i2);
        ins3(o2, j2, t0, t1, t2, i0, i1, i2);
    }

    // inverse-distance weights (reference clamps d^2 at 1e-16), fp32
    if (lane == 0) {
        float w0 = __fdiv_rn(1.0f, fmaxf(t0, 1e-16f));
        float w1 = __fdiv_rn(1.0f, fmaxf(t1, 1e-16f));
        float w2 = __fdiv_rn(1.0f, fmaxf(t2, 1e-16f));
        float inv = __fdiv_rn(1.0f, __fadd_rn(__fadd_rn(w0, w1), w2));
        nbrw[m] = make_float4(w0 * inv, w1 * inv, w2 * inv, 0.f);
        nbri[m] = make_uint4((u32)i0, (u32)i1, (u32)i2, 0u);
    }
}

// ---------------------------------------------------------------------------
// Kernel 4 (MFMA): Z = bf16(x) @ bf16(W1[:256,:])   [4096, 256], no bias.
// ---------------------------------------------------------------------------
__global__ __launch_bounds__(256) void gemm_Z(
    const float* __restrict__ x, const u16* __restrict__ W1T,
    float* __restrict__ Z)
{
    __shared__ alignas(16) u16 Bs[64][40];
    const int tid = threadIdx.x;
    const int w = tid >> 6, l = tid & 63;
    const int bm = blockIdx.x * 128;
    const int bn = blockIdx.y * 64;
    const int lr = l & 15, lg = l >> 4;

    f32x4 acc[2][4];
    #pragma unroll
    for (int mt = 0; mt < 2; ++mt)
        #pragma unroll
        for (int nt = 0; nt < 4; ++nt)
            acc[mt][nt] = (f32x4){0.f, 0.f, 0.f, 0.f};

    const int sc = tid >> 2;
    const int sk = (tid & 3) * 8;

    for (int k0 = 0; k0 < CIN; k0 += 32) {
        *reinterpret_cast<bf16x8*>(&Bs[sc][sk]) =
            *reinterpret_cast<const bf16x8*>(&W1T[(size_t)(bn + sc) * KDIM + k0 + sk]);
        __syncthreads();

        bf16x8 af[2];
        #pragma unroll
        for (int mt = 0; mt < 2; ++mt) {
            const float* xp = x + (size_t)(bm + w * 32 + mt * 16 + lr) * CIN + k0 + lg * 8;
            float4 h0 = *reinterpret_cast<const float4*>(xp);
            float4 h1 = *reinterpret_cast<const float4*>(xp + 4);
            af[mt][0] = (short)f2bf(h0.x); af[mt][1] = (short)f2bf(h0.y);
            af[mt][2] = (short)f2bf(h0.z); af[mt][3] = (short)f2bf(h0.w);
            af[mt][4] = (short)f2bf(h1.x); af[mt][5] = (short)f2bf(h1.y);
            af[mt][6] = (short)f2bf(h1.z); af[mt][7] = (short)f2bf(h1.w);
        }
        #pragma unroll
        for (int nt = 0; nt < 4; ++nt) {
            bf16x8 bf = *reinterpret_cast<const bf16x8*>(&Bs[nt * 16 + lr][lg * 8]);
            #pragma unroll
            for (int mt = 0; mt < 2; ++mt)
                acc[mt][nt] = __builtin_amdgcn_mfma_f32_16x16x32_bf16(
                    af[mt], bf, acc[mt][nt], 0, 0, 0);
        }
        __syncthreads();
    }

    #pragma unroll
    for (int nt = 0; nt < 4; ++nt) {
        const int col = bn + nt * 16 + lr;
        #pragma unroll
        for (int mt = 0; mt < 2; ++mt)
            #pragma unroll
            for (int i = 0; i < 4; ++i) {
                const int row = bm + w * 32 + mt * 16 + lg * 4 + i;
                Z[(size_t)row * HDIM + col] = acc[mt][nt][i];
            }
    }
}

// ---------------------------------------------------------------------------
// Kernel 5 (MFMA): S = bf16(x_skip) @ bf16(W1[256:,:]); epilogue fuses the
// knn interpolation: H = relu(S + sum_k w_k Z[i_k] + b1), H stored bf16.
// Gather indices clamped to [0,4095] (defensive: bugs -> absmax, not fault).
// ---------------------------------------------------------------------------
__global__ __launch_bounds__(256) void gemm_SH(
    const float* __restrict__ x_skip, const u16* __restrict__ W1T,
    const float* __restrict__ b1, const float* __restrict__ Z,
    const float4* __restrict__ nbrw, const uint4* __restrict__ nbri,
    u16* __restrict__ H)
{
    __shared__ alignas(16) u16 Bs[64][40];
    const int tid = threadIdx.x;
    const int w = tid >> 6, l = tid & 63;
    const int bm = blockIdx.x * 128;
    const int bn = blockIdx.y * 64;
    const int lr = l & 15, lg = l >> 4;

    f32x4 acc[2][4];
    #pragma unroll
    for (int mt = 0; mt < 2; ++mt)
        #pragma unroll
        for (int nt = 0; nt < 4; ++nt)
            acc[mt][nt] = (f32x4){0.f, 0.f, 0.f, 0.f};

    const int sc = tid >> 2;
    const int sk = (tid & 3) * 8;

    for (int k0 = 0; k0 < CSK; k0 += 32) {
        *reinterpret_cast<bf16x8*>(&Bs[sc][sk]) =
            *reinterpret_cast<const bf16x8*>(&W1T[(size_t)(bn + sc) * KDIM + CIN + k0 + sk]);
        __syncthreads();

        bf16x8 af[2];
        #pragma unroll
        for (int mt = 0; mt < 2; ++mt) {
            const float* xp = x_skip + (size_t)(bm + w * 32 + mt * 16 + lr) * CSK + k0 + lg * 8;
            float4 h0 = *reinterpret_cast<const float4*>(xp);
            float4 h1 = *reinterpret_cast<const float4*>(xp + 4);
            af[mt][0] = (short)f2bf(h0.x); af[mt][1] = (short)f2bf(h0.y);
            af[mt][2] = (short)f2bf(h0.z); af[mt][3] = (short)f2bf(h0.w);
            af[mt][4] = (short)f2bf(h1.x); af[mt][5] = (short)f2bf(h1.y);
            af[mt][6] = (short)f2bf(h1.z); af[mt][7] = (short)f2bf(h1.w);
        }
        #pragma unroll
        for (int nt = 0; nt < 4; ++nt) {
            bf16x8 bf = *reinterpret_cast<const bf16x8*>(&Bs[nt * 16 + lr][lg * 8]);
            #pragma unroll
            for (int mt = 0; mt < 2; ++mt)
                acc[mt][nt] = __builtin_amdgcn_mfma_f32_16x16x32_bf16(
                    af[mt], bf, acc[mt][nt], 0, 0, 0);
        }
        __syncthreads();
    }

    // epilogue: blend interpolated Z rows + bias + relu -> H (bf16)
    #pragma unroll
    for (int mt = 0; mt < 2; ++mt) {
        #pragma unroll
        for (int i = 0; i < 4; ++i) {
            const int row = bm + w * 32 + mt * 16 + lg * 4 + i;
            const float4 wv = nbrw[row];
            const uint4  iv = nbri[row];
            const float* z0 = Z + (size_t)(iv.x & 4095u) * HDIM;  // clamp: no OOB
            const float* z1 = Z + (size_t)(iv.y & 4095u) * HDIM;
            const float* z2 = Z + (size_t)(iv.z & 4095u) * HDIM;
            #pragma unroll
            for (int nt = 0; nt < 4; ++nt) {
                const int col = bn + nt * 16 + lr;
                float zb = wv.x * z0[col] + wv.y * z1[col] + wv.z * z2[col];
                float v = acc[mt][nt][i] + zb + b1[col];
                H[(size_t)row * HDIM + col] = f2bf(v > 0.f ? v : 0.f);
            }
        }
    }
}

// ---------------------------------------------------------------------------
// Kernel 6 (MFMA): out = H @ W2 + b2.  H bf16 [16384,256], out f32.
// ---------------------------------------------------------------------------
__global__ __launch_bounds__(256) void gemm2_mfma(
    const u16* __restrict__ H, const float* __restrict__ W2,
    const float* __restrict__ b2, float* __restrict__ out)
{
    __shared__ alignas(16) u16 Bs[64][40];
    const int tid = threadIdx.x;
    const int w = tid >> 6, l = tid & 63;
    const int bm = blockIdx.x * 128;
    const int bn = blockIdx.y * 64;
    const int lr = l & 15, lg = l >> 4;

    f32x4 acc[2][4];
    #pragma unroll
    for (int mt = 0; mt < 2; ++mt)
        #pragma unroll
        for (int nt = 0; nt < 4; ++nt)
            acc[mt][nt] = (f32x4){0.f, 0.f, 0.f, 0.f};

    const int sc = tid >> 2;
    const int sk = (tid & 3) * 8;

    for (int k0 = 0; k0 < HDIM; k0 += 32) {
        #pragma unroll
        for (int j = 0; j < 8; ++j)
            Bs[sc][sk + j] = f2bf(W2[(size_t)(k0 + sk + j) * HDIM + bn + sc]);
        __syncthreads();

        bf16x8 af[2];
        #pragma unroll
        for (int mt = 0; mt < 2; ++mt) {
            const int row = bm + w * 32 + mt * 16 + lr;
            af[mt] = *reinterpret_cast<const bf16x8*>(H + (size_t)row * HDIM + k0 + lg * 8);
        }
        #pragma unroll
        for (int nt = 0; nt < 4; ++nt) {
            bf16x8 bf = *reinterpret_cast<const bf16x8*>(&Bs[nt * 16 + lr][lg * 8]);
            #pragma unroll
            for (int mt = 0; mt < 2; ++mt)
                acc[mt][nt] = __builtin_amdgcn_mfma_f32_16x16x32_bf16(
                    af[mt], bf, acc[mt][nt], 0, 0, 0);
        }
        __syncthreads();
    }

    #pragma unroll
    for (int nt = 0; nt < 4; ++nt) {
        const int col = bn + nt * 16 + lr;
        const float bias = b2[col];
        #pragma unroll
        for (int mt = 0; mt < 2; ++mt)
            #pragma unroll
            for (int i = 0; i < 4; ++i) {
                const int row = bm + w * 32 + mt * 16 + lg * 4 + i;
                out[(size_t)row * HDIM + col] = acc[mt][nt][i] + bias;
            }
    }
}

// ---------------------------------------------------------------------------
extern "C" void kernel_launch(void* const* d_in, const int* in_sizes, int n_in,
                              void* d_out, int out_size, void* d_ws, size_t ws_size,
                              hipStream_t stream) {
    const float* x        = (const float*)d_in[0];
    const float* pos      = (const float*)d_in[1];
    const float* x_skip   = (const float*)d_in[2];
    const float* pos_skip = (const float*)d_in[3];
    const float* W1       = (const float*)d_in[4];
    const float* b1       = (const float*)d_in[5];
    const float* W2       = (const float*)d_in[6];
    const float* b2       = (const float*)d_in[7];

    // d_ws (12.5 MiB, proven): Hbuf 8M | Z 4M | nbrw 256K | nbri 256K
    u16*    Hbuf = (u16*)d_ws;                               // [16384][256] bf16
    float*  Z    = (float*)((char*)d_ws + (8u << 20));       // [4096][256] f32
    float4* nbrw = (float4*)((char*)d_ws + (12u << 20));
    uint4*  nbri = (uint4*)((char*)d_ws + (12u << 20) + (256u << 10));

    // d_out scratch (16 MiB total; all dead before gemm2 writes out):
    float4* candV = (float4*)d_out;                          // [32][16384] f32x4 = 8 MiB
    u32*    nbrm  = (u32*)((char*)d_out + (13u << 20));      // [16384] u32 = 64 KiB
    u16*    W1T   = (u16*)((char*)d_out + (14u << 20));      // [256][384] bf16 = 192 KiB
    float*  out   = (float*)d_out;

    prep_w1t   <<<256, 384, 0, stream>>>(W1, W1T);
    knn_scanV  <<<dim3(32, NSHARD), 256, 0, stream>>>(pos, pos_skip, candV);
    knn_mask   <<<64, 256, 0, stream>>>(candV, nbrm);
    knn_rescan <<<4096, 256, 0, stream>>>(pos, pos_skip, nbrm, nbrw, nbri);
    gemm_Z     <<<dim3(32, 4), 256, 0, stream>>>(x, W1T, Z);
    gemm_SH    <<<dim3(128, 4), 256, 0, stream>>>(x_skip, W1T, b1, Z, nbrw, nbri, Hbuf);
    gemm2_mfma <<<dim3(128, 4), 256, 0, stream>>>(Hbuf, W2, b2, out);
}

// Round 14
// 91.018 us; speedup vs baseline: 1.5830x; 1.5830x over previous
//
#include <hip/hip_runtime.h>
#include <hip/hip_bf16.h>

#define N_PTS 4096
#define M_PTS 16384
#define CIN   256
#define CSK   128
#define KDIM  384   // CIN + CSK
#define HDIM  256
#define NSHARD 32
#define SHPTS (N_PTS / NSHARD)   // 128

typedef unsigned int  u32;
typedef unsigned short u16;
typedef __attribute__((ext_vector_type(8))) short bf16x8;
typedef __attribute__((ext_vector_type(4))) float f32x4;

__device__ __forceinline__ u16 f2bf(float f) {
    union { float f; u32 i; } w; w.f = f;
    u32 x = w.i;
    u32 r = x + 0x7fffu + ((x >> 16) & 1u);   // RTNE
    return (u16)(r >> 16);
}

// strict "better" with lower-index tie-break (stable-sort semantics)
__device__ __forceinline__ bool ltk(float s, int p, float t, int i) {
    return (s < t) || (s == t && p < i);
}
__device__ __forceinline__ void ins3(float s, int p,
                                     float& t0, float& t1, float& t2,
                                     int& i0, int& i1, int& i2) {
    if (ltk(s, p, t2, i2)) {
        if (ltk(s, p, t1, i1)) {
            t2 = t1; i2 = i1;
            if (ltk(s, p, t0, i0)) { t1 = t0; i1 = i0; t0 = s; i0 = p; }
            else                   { t1 = s;  i1 = p; }
        } else { t2 = s; i2 = p; }
    }
}

// branchless sorted top-3 insert, strict < (ascending-index stream => stable)
#define INS3BL(s, p, t0, t1, t2, i0, i1, i2)                              \
    {                                                                     \
        float _o0 = t0, _o1 = t1, _o2 = t2;                               \
        int _a0 = i0, _a1 = i1, _a2 = i2;                                 \
        bool _c0 = (s) < _o0, _c1 = (s) < _o1, _c2 = (s) < _o2;           \
        t0 = _c0 ? (s) : _o0;              i0 = _c0 ? (p) : _a0;          \
        t1 = _c0 ? _o0 : (_c1 ? (s) : _o1); i1 = _c0 ? _a0 : (_c1 ? (p) : _a1); \
        t2 = _c1 ? _o1 : (_c2 ? (s) : _o2); i2 = _c1 ? _a1 : (_c2 ? (p) : _a2); \
    }

// branchless top-3 insert: values via min/med3 (3 VALU), indices via cmp+sel.
// Exactly equivalent to INS3BL incl. tie handling (strict <, stable).
// Proven bit-exact in round 9.
#define INS3MM(s, p, t0, t1, t2, i0, i1, i2)                              \
    {                                                                     \
        bool _c0 = (s) < t0, _c1 = (s) < t1, _c2 = (s) < t2;              \
        int _oi0 = i0, _oi1 = i1;                                         \
        i0 = _c0 ? (p) : i0;                                              \
        i1 = _c0 ? _oi0 : (_c1 ? (p) : i1);                               \
        i2 = _c1 ? _oi1 : (_c2 ? (p) : i2);                               \
        float _ot0 = t0, _ot1 = t1;                                       \
        t0 = fminf(t0, (s));                                              \
        t1 = __builtin_amdgcn_fmed3f(_ot0, t1, (s));                      \
        t2 = __builtin_amdgcn_fmed3f(_ot1, t2, (s));                      \
    }

// ---------------------------------------------------------------------------
// Kernel 1: sharded 3-NN scan (round-8 proven geometry: ONE query per thread,
// 4 interleaved chains, shard points staged in LDS). INS3MM insert.
// Bit-exact fp32 d^2 = (|q|^2 - 2*fma(qz,pz,fma(qy,py,qx*px))) + |p|^2.
// Output TRANSPOSED: candT[(sh*3+k)*M + m]  (coalesced write AND read).
// ---------------------------------------------------------------------------
__global__ __launch_bounds__(256, 8) void knn_scan(
    const float* __restrict__ pos,
    const float* __restrict__ pos_skip,
    uint2* __restrict__ candT)
{
    __shared__ float4 spts[SHPTS];     // 128 x 16B = 2 KB
    const int tid = threadIdx.x;
    const int m  = blockIdx.x * 256 + tid;
    const int sh = blockIdx.y;
    const int pbase = sh * SHPTS;

    if (tid < SHPTS) {
        const int i = pbase + tid;
        float px = pos[3 * i], py = pos[3 * i + 1], pz = pos[3 * i + 2];
        float pn = __fadd_rn(__fadd_rn(__fmul_rn(px, px), __fmul_rn(py, py)),
                             __fmul_rn(pz, pz));
        spts[tid] = make_float4(px, py, pz, pn);
    }

    const float qx = pos_skip[3 * m];
    const float qy = pos_skip[3 * m + 1];
    const float qz = pos_skip[3 * m + 2];
    const float qn = __fadd_rn(__fadd_rn(__fmul_rn(qx, qx), __fmul_rn(qy, qy)),
                               __fmul_rn(qz, qz));
    __syncthreads();

    float e0[4], e1[4], e2[4];
    int   a0[4], a1[4], a2[4];
    #pragma unroll
    for (int c = 0; c < 4; ++c) {
        e0[c] = 3.4e38f; e1[c] = 3.4e38f; e2[c] = 3.4e38f;
        a0[c] = 0x7fffffff; a1[c] = 0x7fffffff; a2[c] = 0x7fffffff;
    }

    #pragma unroll 8
    for (int j = 0; j < SHPTS; ++j) {
        float4 v = spts[j];            // uniform broadcast read
        // b = q.p as fma chain (k ascending), bit-exact vs reference
        float b = __fmaf_rn(qz, v.z, __fmaf_rn(qy, v.y, __fmul_rn(qx, v.x)));
        // s = (qn - 2b) + pn ; qn - 2b == fma(-2, b, qn) exactly (2b exact)
        float s = __fadd_rn(__fmaf_rn(-2.0f, b, qn), v.w);
        const int p = pbase + j;
        const int c = j & 3;
        INS3MM(s, p, e0[c], e1[c], e2[c], a0[c], a1[c], a2[c]);
    }
    // merge chains 1..3 into chain 0 (value, then lower-index tie-break)
    #pragma unroll
    for (int c = 1; c < 4; ++c) {
        ins3(e0[c], a0[c], e0[0], e1[0], e2[0], a0[0], a1[0], a2[0]);
        ins3(e1[c], a1[c], e0[0], e1[0], e2[0], a0[0], a1[0], a2[0]);
        ins3(e2[c], a2[c], e0[0], e1[0], e2[0], a0[0], a1[0], a2[0]);
    }

    candT[(size_t)(sh * 3 + 0) * M_PTS + m] = make_uint2(__float_as_uint(e0[0]), (u32)a0[0]);
    candT[(size_t)(sh * 3 + 1) * M_PTS + m] = make_uint2(__float_as_uint(e1[0]), (u32)a1[0]);
    candT[(size_t)(sh * 3 + 2) * M_PTS + m] = make_uint2(__float_as_uint(e2[0]), (u32)a2[0]);
}

// ---------------------------------------------------------------------------
// Kernel 2: per-thread merge of 32 shard top-3 lists -> normalized weights+idx.
// Shard-ascending + k-ascending insert order with strict < == stable order.
// Coalesced candT reads (fixed (sh,k): consecutive m -> consecutive uint2).
// ---------------------------------------------------------------------------
__global__ __launch_bounds__(256) void knn_merge(
    const uint2* __restrict__ candT,   // [32][3][M]
    float4* __restrict__ nbrw,         // [M] (w0,w1,w2,-) normalized
    uint4* __restrict__ nbri)          // [M] (i0,i1,i2,-)
{
    const int m = blockIdx.x * 256 + threadIdx.x;

    float t0 = 3.4e38f, t1 = 3.4e38f, t2 = 3.4e38f;
    int   i0 = 0x7fffffff, i1 = 0x7fffffff, i2 = 0x7fffffff;

    #pragma unroll
    for (int sh = 0; sh < NSHARD; ++sh) {
        #pragma unroll
        for (int k = 0; k < 3; ++k) {
            uint2 v = candT[(size_t)(sh * 3 + k) * M_PTS + m];
            float s = __uint_as_float(v.x);
            const int p = (int)v.y;
            INS3BL(s, p, t0, t1, t2, i0, i1, i2);
        }
    }

    float w0 = __fdiv_rn(1.0f, fmaxf(t0, 1e-16f));
    float w1 = __fdiv_rn(1.0f, fmaxf(t1, 1e-16f));
    float w2 = __fdiv_rn(1.0f, fmaxf(t2, 1e-16f));
    float inv = __fdiv_rn(1.0f, __fadd_rn(__fadd_rn(w0, w1), w2));
    nbrw[m] = make_float4(w0 * inv, w1 * inv, w2 * inv, 0.f);
    nbri[m] = make_uint4((u32)i0, (u32)i1, (u32)i2, 0u);
}

// ---------------------------------------------------------------------------
// Kernel 3 (MFMA): Z = bf16(x) @ bf16(W1[:256,:])   [4096, 256], no bias.
// W1 converted to bf16 at LDS-stage time (in-kernel, round-6 proven pattern).
// ---------------------------------------------------------------------------
__global__ __launch_bounds__(256) void gemm_Z(
    const float* __restrict__ x, const float* __restrict__ W1,
    float* __restrict__ Z)
{
    __shared__ alignas(16) u16 Bs[64][40];
    const int tid = threadIdx.x;
    const int w = tid >> 6, l = tid & 63;
    const int bm = blockIdx.x * 128;
    const int bn = blockIdx.y * 64;
    const int lr = l & 15, lg = l >> 4;

    f32x4 acc[2][4];
    #pragma unroll
    for (int mt = 0; mt < 2; ++mt)
        #pragma unroll
        for (int nt = 0; nt < 4; ++nt)
            acc[mt][nt] = (f32x4){0.f, 0.f, 0.f, 0.f};

    const int sc = tid >> 2;
    const int sk = (tid & 3) * 8;

    for (int k0 = 0; k0 < CIN; k0 += 32) {
        #pragma unroll
        for (int j = 0; j < 8; ++j)
            Bs[sc][sk + j] = f2bf(W1[(size_t)(k0 + sk + j) * HDIM + bn + sc]);
        __syncthreads();

        bf16x8 af[2];
        #pragma unroll
        for (int mt = 0; mt < 2; ++mt) {
            const float* xp = x + (size_t)(bm + w * 32 + mt * 16 + lr) * CIN + k0 + lg * 8;
            float4 h0 = *reinterpret_cast<const float4*>(xp);
            float4 h1 = *reinterpret_cast<const float4*>(xp + 4);
            af[mt][0] = (short)f2bf(h0.x); af[mt][1] = (short)f2bf(h0.y);
            af[mt][2] = (short)f2bf(h0.z); af[mt][3] = (short)f2bf(h0.w);
            af[mt][4] = (short)f2bf(h1.x); af[mt][5] = (short)f2bf(h1.y);
            af[mt][6] = (short)f2bf(h1.z); af[mt][7] = (short)f2bf(h1.w);
        }
        #pragma unroll
        for (int nt = 0; nt < 4; ++nt) {
            bf16x8 bf = *reinterpret_cast<const bf16x8*>(&Bs[nt * 16 + lr][lg * 8]);
            #pragma unroll
            for (int mt = 0; mt < 2; ++mt)
                acc[mt][nt] = __builtin_amdgcn_mfma_f32_16x16x32_bf16(
                    af[mt], bf, acc[mt][nt], 0, 0, 0);
        }
        __syncthreads();
    }

    #pragma unroll
    for (int nt = 0; nt < 4; ++nt) {
        const int col = bn + nt * 16 + lr;
        #pragma unroll
        for (int mt = 0; mt < 2; ++mt)
            #pragma unroll
            for (int i = 0; i < 4; ++i) {
                const int row = bm + w * 32 + mt * 16 + lg * 4 + i;
                Z[(size_t)row * HDIM + col] = acc[mt][nt][i];
            }
    }
}

// ---------------------------------------------------------------------------
// Kernel 4 (MFMA): S = bf16(x_skip) @ bf16(W1[256:,:]); epilogue fuses the
// knn interpolation: H = relu(S + sum_k w_k Z[i_k] + b1), H stored bf16.
// Gather indices clamped (defensive: bugs -> absmax, not fault).
// ---------------------------------------------------------------------------
__global__ __launch_bounds__(256) void gemm_SH(
    const float* __restrict__ x_skip, const float* __restrict__ W1,
    const float* __restrict__ b1, const float* __restrict__ Z,
    const float4* __restrict__ nbrw, const uint4* __restrict__ nbri,
    u16* __restrict__ H)
{
    __shared__ alignas(16) u16 Bs[64][40];
    const int tid = threadIdx.x;
    const int w = tid >> 6, l = tid & 63;
    const int bm = blockIdx.x * 128;
    const int bn = blockIdx.y * 64;
    const int lr = l & 15, lg = l >> 4;

    f32x4 acc[2][4];
    #pragma unroll
    for (int mt = 0; mt < 2; ++mt)
        #pragma unroll
        for (int nt = 0; nt < 4; ++nt)
            acc[mt][nt] = (f32x4){0.f, 0.f, 0.f, 0.f};

    const int sc = tid >> 2;
    const int sk = (tid & 3) * 8;

    for (int k0 = 0; k0 < CSK; k0 += 32) {
        #pragma unroll
        for (int j = 0; j < 8; ++j)
            Bs[sc][sk + j] = f2bf(W1[(size_t)(CIN + k0 + sk + j) * HDIM + bn + sc]);
        __syncthreads();

        bf16x8 af[2];
        #pragma unroll
        for (int mt = 0; mt < 2; ++mt) {
            const float* xp = x_skip + (size_t)(bm + w * 32 + mt * 16 + lr) * CSK + k0 + lg * 8;
            float4 h0 = *reinterpret_cast<const float4*>(xp);
            float4 h1 = *reinterpret_cast<const float4*>(xp + 4);
            af[mt][0] = (short)f2bf(h0.x); af[mt][1] = (short)f2bf(h0.y);
            af[mt][2] = (short)f2bf(h0.z); af[mt][3] = (short)f2bf(h0.w);
            af[mt][4] = (short)f2bf(h1.x); af[mt][5] = (short)f2bf(h1.y);
            af[mt][6] = (short)f2bf(h1.z); af[mt][7] = (short)f2bf(h1.w);
        }
        #pragma unroll
        for (int nt = 0; nt < 4; ++nt) {
            bf16x8 bf = *reinterpret_cast<const bf16x8*>(&Bs[nt * 16 + lr][lg * 8]);
            #pragma unroll
            for (int mt = 0; mt < 2; ++mt)
                acc[mt][nt] = __builtin_amdgcn_mfma_f32_16x16x32_bf16(
                    af[mt], bf, acc[mt][nt], 0, 0, 0);
        }
        __syncthreads();
    }

    // epilogue: blend interpolated Z rows + bias + relu -> H (bf16)
    #pragma unroll
    for (int mt = 0; mt < 2; ++mt) {
        #pragma unroll
        for (int i = 0; i < 4; ++i) {
            const int row = bm + w * 32 + mt * 16 + lg * 4 + i;
            const float4 wv = nbrw[row];
            const uint4  iv = nbri[row];
            const float* z0 = Z + (size_t)(iv.x & 4095u) * HDIM;  // clamp: no OOB
            const float* z1 = Z + (size_t)(iv.y & 4095u) * HDIM;
            const float* z2 = Z + (size_t)(iv.z & 4095u) * HDIM;
            #pragma unroll
            for (int nt = 0; nt < 4; ++nt) {
                const int col = bn + nt * 16 + lr;
                float zb = wv.x * z0[col] + wv.y * z1[col] + wv.z * z2[col];
                float v = acc[mt][nt][i] + zb + b1[col];
                H[(size_t)row * HDIM + col] = f2bf(v > 0.f ? v : 0.f);
            }
        }
    }
}

// ---------------------------------------------------------------------------
// Kernel 5 (MFMA): out = H @ W2 + b2.  H bf16 [16384,256], out f32.
// ---------------------------------------------------------------------------
__global__ __launch_bounds__(256) void gemm2_mfma(
    const u16* __restrict__ H, const float* __restrict__ W2,
    const float* __restrict__ b2, float* __restrict__ out)
{
    __shared__ alignas(16) u16 Bs[64][40];
    const int tid = threadIdx.x;
    const int w = tid >> 6, l = tid & 63;
    const int bm = blockIdx.x * 128;
    const int bn = blockIdx.y * 64;
    const int lr = l & 15, lg = l >> 4;

    f32x4 acc[2][4];
    #pragma unroll
    for (int mt = 0; mt < 2; ++mt)
        #pragma unroll
        for (int nt = 0; nt < 4; ++nt)
            acc[mt][nt] = (f32x4){0.f, 0.f, 0.f, 0.f};

    const int sc = tid >> 2;
    const int sk = (tid & 3) * 8;

    for (int k0 = 0; k0 < HDIM; k0 += 32) {
        #pragma unroll
        for (int j = 0; j < 8; ++j)
            Bs[sc][sk + j] = f2bf(W2[(size_t)(k0 + sk + j) * HDIM + bn + sc]);
        __syncthreads();

        bf16x8 af[2];
        #pragma unroll
        for (int mt = 0; mt < 2; ++mt) {
            const int row = bm + w * 32 + mt * 16 + lr;
            af[mt] = *reinterpret_cast<const bf16x8*>(H + (size_t)row * HDIM + k0 + lg * 8);
        }
        #pragma unroll
        for (int nt = 0; nt < 4; ++nt) {
            bf16x8 bf = *reinterpret_cast<const bf16x8*>(&Bs[nt * 16 + lr][lg * 8]);
            #pragma unroll
            for (int mt = 0; mt < 2; ++mt)
                acc[mt][nt] = __builtin_amdgcn_mfma_f32_16x16x32_bf16(
                    af[mt], bf, acc[mt][nt], 0, 0, 0);
        }
        __syncthreads();
    }

    #pragma unroll
    for (int nt = 0; nt < 4; ++nt) {
        const int col = bn + nt * 16 + lr;
        const float bias = b2[col];
        #pragma unroll
        for (int mt = 0; mt < 2; ++mt)
            #pragma unroll
            for (int i = 0; i < 4; ++i) {
                const int row = bm + w * 32 + mt * 16 + lg * 4 + i;
                out[(size_t)row * HDIM + col] = acc[mt][nt][i] + bias;
            }
    }
}

// ---------------------------------------------------------------------------
extern "C" void kernel_launch(void* const* d_in, const int* in_sizes, int n_in,
                              void* d_out, int out_size, void* d_ws, size_t ws_size,
                              hipStream_t stream) {
    const float* x        = (const float*)d_in[0];
    const float* pos      = (const float*)d_in[1];
    const float* x_skip   = (const float*)d_in[2];
    const float* pos_skip = (const float*)d_in[3];
    const float* W1       = (const float*)d_in[4];
    const float* b1       = (const float*)d_in[5];
    const float* W2       = (const float*)d_in[6];
    const float* b2       = (const float*)d_in[7];

    // d_ws (12.5 MiB, proven): Hbuf 8M | Z 4M | nbrw 256K | nbri 256K
    u16*    Hbuf = (u16*)d_ws;                               // [16384][256] bf16
    float*  Z    = (float*)((char*)d_ws + (8u << 20));       // [4096][256] f32
    float4* nbrw = (float4*)((char*)d_ws + (12u << 20));
    uint4*  nbri = (uint4*)((char*)d_ws + (12u << 20) + (256u << 10));

    // d_out scratch (dead before gemm2 writes out):
    uint2* candT = (uint2*)d_out;                            // [32][3][16384] = 12.58 MB
    float* out   = (float*)d_out;

    knn_scan  <<<dim3(64, NSHARD), 256, 0, stream>>>(pos, pos_skip, candT);
    knn_merge <<<64, 256, 0, stream>>>(candT, nbrw, nbri);
    gemm_Z    <<<dim3(32, 4), 256, 0, stream>>>(x, W1, Z);
    gemm_SH   <<<dim3(128, 4), 256, 0, stream>>>(x_skip, W1, b1, Z, nbrw, nbri, Hbuf);
    gemm2_mfma<<<dim3(128, 4), 256, 0, stream>>>(Hbuf, W2, b2, out);
}

// Round 15
// 70.364 us; speedup vs baseline: 2.0477x; 1.2935x over previous
//
#include <hip/hip_runtime.h>
#include <hip/hip_bf16.h>

#define N_PTS 4096
#define M_PTS 16384
#define CIN   256
#define CSK   128
#define KDIM  384   // CIN + CSK
#define HDIM  256
#define NSHARD 32
#define SHPTS (N_PTS / NSHARD)   // 128

typedef unsigned int  u32;
typedef unsigned short u16;
typedef __attribute__((ext_vector_type(8))) short bf16x8;
typedef __attribute__((ext_vector_type(4))) float f32x4;

__device__ __forceinline__ u16 f2bf(float f) {
    union { float f; u32 i; } w; w.f = f;
    u32 x = w.i;
    u32 r = x + 0x7fffu + ((x >> 16) & 1u);   // RTNE
    return (u16)(r >> 16);
}

// strict "better" with lower-index tie-break (stable-sort semantics)
__device__ __forceinline__ bool ltk(float s, int p, float t, int i) {
    return (s < t) || (s == t && p < i);
}
__device__ __forceinline__ void ins3(float s, int p,
                                     float& t0, float& t1, float& t2,
                                     int& i0, int& i1, int& i2) {
    if (ltk(s, p, t2, i2)) {
        if (ltk(s, p, t1, i1)) {
            t2 = t1; i2 = i1;
            if (ltk(s, p, t0, i0)) { t1 = t0; i1 = i0; t0 = s; i0 = p; }
            else                   { t1 = s;  i1 = p; }
        } else { t2 = s; i2 = p; }
    }
}

// branchless sorted top-3 insert, strict < (ascending-index stream => stable)
#define INS3BL(s, p, t0, t1, t2, i0, i1, i2)                              \
    {                                                                     \
        float _o0 = t0, _o1 = t1, _o2 = t2;                               \
        int _a0 = i0, _a1 = i1, _a2 = i2;                                 \
        bool _c0 = (s) < _o0, _c1 = (s) < _o1, _c2 = (s) < _o2;           \
        t0 = _c0 ? (s) : _o0;              i0 = _c0 ? (p) : _a0;          \
        t1 = _c0 ? _o0 : (_c1 ? (s) : _o1); i1 = _c0 ? _a0 : (_c1 ? (p) : _a1); \
        t2 = _c1 ? _o1 : (_c2 ? (s) : _o2); i2 = _c1 ? _a1 : (_c2 ? (p) : _a2); \
    }

// branchless top-3 insert: values via min/med3, indices via cmp+sel.
// Proven bit-exact (round 9/14). Strict <, stable for ascending-index streams.
#define INS3MM(s, p, t0, t1, t2, i0, i1, i2)                              \
    {                                                                     \
        bool _c0 = (s) < t0, _c1 = (s) < t1, _c2 = (s) < t2;              \
        int _oi0 = i0, _oi1 = i1;                                         \
        i0 = _c0 ? (p) : i0;                                              \
        i1 = _c0 ? _oi0 : (_c1 ? (p) : i1);                               \
        i2 = _c1 ? _oi1 : (_c2 ? (p) : i2);                               \
        float _ot0 = t0, _ot1 = t1;                                       \
        t0 = fminf(t0, (s));                                              \
        t1 = __builtin_amdgcn_fmed3f(_ot0, t1, (s));                      \
        t2 = __builtin_amdgcn_fmed3f(_ot1, t2, (s));                      \
    }

// ---------------------------------------------------------------------------
// Kernel 1: MIN-ONLY sharded scan. 2 queries/thread (one LDS broadcast read
// serves both), 2 min-chains per query. 6 VALU ops/pair (5 dist + 1 fmin).
// Bit-exact fp32 d^2 = (|q|^2 - 2*fma(qz,pz,fma(qy,py,qx*px))) + |p|^2.
// fminf is exact & order-independent -> candM[sh*M+m] = exact shard min.
// ---------------------------------------------------------------------------
__global__ __launch_bounds__(256, 8) void knn_scanM(
    const float* __restrict__ pos,
    const float* __restrict__ pos_skip,
    float* __restrict__ candM)
{
    __shared__ float4 spts[SHPTS];     // 128 x 16B = 2 KB
    const int tid = threadIdx.x;
    const int sh = blockIdx.y;
    const int pbase = sh * SHPTS;
    const int m0 = blockIdx.x * 512 + tid;
    const int m1 = m0 + 256;

    if (tid < SHPTS) {
        const int i = pbase + tid;
        float px = pos[3 * i], py = pos[3 * i + 1], pz = pos[3 * i + 2];
        float pn = __fadd_rn(__fadd_rn(__fmul_rn(px, px), __fmul_rn(py, py)),
                             __fmul_rn(pz, pz));
        spts[tid] = make_float4(px, py, pz, pn);
    }

    const float qx0 = pos_skip[3 * m0];
    const float qy0 = pos_skip[3 * m0 + 1];
    const float qz0 = pos_skip[3 * m0 + 2];
    const float qn0 = __fadd_rn(__fadd_rn(__fmul_rn(qx0, qx0), __fmul_rn(qy0, qy0)),
                                __fmul_rn(qz0, qz0));
    const float qx1 = pos_skip[3 * m1];
    const float qy1 = pos_skip[3 * m1 + 1];
    const float qz1 = pos_skip[3 * m1 + 2];
    const float qn1 = __fadd_rn(__fadd_rn(__fmul_rn(qx1, qx1), __fmul_rn(qy1, qy1)),
                                __fmul_rn(qz1, qz1));
    __syncthreads();

    float e[2][2];
    e[0][0] = 3.4e38f; e[0][1] = 3.4e38f;
    e[1][0] = 3.4e38f; e[1][1] = 3.4e38f;

    #pragma unroll 8
    for (int j = 0; j < SHPTS; ++j) {
        float4 v = spts[j];            // wave-uniform broadcast read
        const int c = j & 1;
        {
            float b = __fmaf_rn(qz0, v.z, __fmaf_rn(qy0, v.y, __fmul_rn(qx0, v.x)));
            float s = __fadd_rn(__fmaf_rn(-2.0f, b, qn0), v.w);
            e[0][c] = fminf(e[0][c], s);
        }
        {
            float b = __fmaf_rn(qz1, v.z, __fmaf_rn(qy1, v.y, __fmul_rn(qx1, v.x)));
            float s = __fadd_rn(__fmaf_rn(-2.0f, b, qn1), v.w);
            e[1][c] = fminf(e[1][c], s);
        }
    }

    candM[(size_t)sh * M_PTS + m0] = fminf(e[0][0], e[0][1]);
    candM[(size_t)sh * M_PTS + m1] = fminf(e[1][0], e[1][1]);
}

// ---------------------------------------------------------------------------
// Kernel 2: per-thread shard selection. Pick the 3 smallest (min, sh) keys
// (INS3BL over ascending sh + strict < == (min,sh) lexicographic).
// THEOREM: the exact (value,index) top-3 points lie in these 3 shards.
//   Any point p in a non-selected shard D has v_p >= min_D >= each selected
//   shard's min; equal-value cases resolve by index (shard-ordered index
//   ranges) -> p is (value,index)-worse than the 3 selected min-points.
// shsel[m] = s0 | s1<<8 | s2<<16.
// ---------------------------------------------------------------------------
__global__ __launch_bounds__(256) void knn_maskS(
    const float* __restrict__ candM,
    u32* __restrict__ shsel)
{
    const int m = blockIdx.x * 256 + threadIdx.x;
    float t0 = 3.4e38f, t1 = 3.4e38f, t2 = 3.4e38f;
    int   s0 = 63, s1 = 63, s2 = 63;
    #pragma unroll
    for (int sh = 0; sh < NSHARD; ++sh) {
        float mn = candM[(size_t)sh * M_PTS + m];   // coalesced
        INS3BL(mn, sh, t0, t1, t2, s0, s1, s2);
    }
    shsel[m] = (u32)s0 | ((u32)s1 << 8) | ((u32)s2 << 16);
}

// ---------------------------------------------------------------------------
// Kernel 3: rescan the 3 selected shards + merge + weights. 4 threads per
// query (slots 0..2 scan one shard each with proven INS3MM over ascending
// indices; slot 3 idle); LDS holds per-slot triples; slot 0 merges with
// ltk-ins3 ((value,index) total order -> exact regardless of slot order).
// All per-thread / LDS code -- no wave-per-query, no shuffles.
// ---------------------------------------------------------------------------
__global__ __launch_bounds__(256) void knn_rescan_merge(
    const float* __restrict__ pos,
    const float* __restrict__ pos_skip,
    const u32* __restrict__ shsel,
    float4* __restrict__ nbrw, uint4* __restrict__ nbri)
{
    __shared__ float sv[64][3][3];
    __shared__ int   si[64][3][3];
    const int tid  = threadIdx.x;
    const int ql   = tid >> 2;
    const int slot = tid & 3;
    const int m = blockIdx.x * 64 + ql;   // 256 blocks * 64 queries

    const u32 sel = shsel[m];

    if (slot < 3) {
        const int sh = (sel >> (8 * slot)) & 63;
        const int pb = sh * SHPTS;

        const float qx = pos_skip[3 * m];
        const float qy = pos_skip[3 * m + 1];
        const float qz = pos_skip[3 * m + 2];
        const float qn = __fadd_rn(__fadd_rn(__fmul_rn(qx, qx), __fmul_rn(qy, qy)),
                                   __fmul_rn(qz, qz));

        float t0 = 3.4e38f, t1 = 3.4e38f, t2 = 3.4e38f;
        int   i0 = 0x7fffffff, i1 = 0x7fffffff, i2 = 0x7fffffff;

        #pragma unroll 4
        for (int j = 0; j < SHPTS; ++j) {
            const int p = pb + j;
            float px = pos[3 * p], py = pos[3 * p + 1], pz = pos[3 * p + 2];
            float pn = __fadd_rn(__fadd_rn(__fmul_rn(px, px), __fmul_rn(py, py)),
                                 __fmul_rn(pz, pz));
            float b = __fmaf_rn(qz, pz, __fmaf_rn(qy, py, __fmul_rn(qx, px)));
            float s = __fadd_rn(__fmaf_rn(-2.0f, b, qn), pn);
            INS3MM(s, p, t0, t1, t2, i0, i1, i2);
        }
        sv[ql][slot][0] = t0; sv[ql][slot][1] = t1; sv[ql][slot][2] = t2;
        si[ql][slot][0] = i0; si[ql][slot][1] = i1; si[ql][slot][2] = i2;
    }
    __syncthreads();

    if (slot == 0) {
        float t0 = 3.4e38f, t1 = 3.4e38f, t2 = 3.4e38f;
        int   i0 = 0x7fffffff, i1 = 0x7fffffff, i2 = 0x7fffffff;
        #pragma unroll
        for (int s = 0; s < 3; ++s)
            #pragma unroll
            for (int k = 0; k < 3; ++k)
                ins3(sv[ql][s][k], si[ql][s][k], t0, t1, t2, i0, i1, i2);

        // inverse-distance weights (reference clamps d^2 at 1e-16), fp32
        float w0 = __fdiv_rn(1.0f, fmaxf(t0, 1e-16f));
        float w1 = __fdiv_rn(1.0f, fmaxf(t1, 1e-16f));
        float w2 = __fdiv_rn(1.0f, fmaxf(t2, 1e-16f));
        float inv = __fdiv_rn(1.0f, __fadd_rn(__fadd_rn(w0, w1), w2));
        nbrw[m] = make_float4(w0 * inv, w1 * inv, w2 * inv, 0.f);
        nbri[m] = make_uint4((u32)i0, (u32)i1, (u32)i2, 0u);
    }
}

// ---------------------------------------------------------------------------
// Kernel 4 (MFMA): Z = bf16(x) @ bf16(W1[:256,:])   [4096, 256], no bias.
// ---------------------------------------------------------------------------
__global__ __launch_bounds__(256) void gemm_Z(
    const float* __restrict__ x, const float* __restrict__ W1,
    float* __restrict__ Z)
{
    __shared__ alignas(16) u16 Bs[64][40];
    const int tid = threadIdx.x;
    const int w = tid >> 6, l = tid & 63;
    const int bm = blockIdx.x * 128;
    const int bn = blockIdx.y * 64;
    const int lr = l & 15, lg = l >> 4;

    f32x4 acc[2][4];
    #pragma unroll
    for (int mt = 0; mt < 2; ++mt)
        #pragma unroll
        for (int nt = 0; nt < 4; ++nt)
            acc[mt][nt] = (f32x4){0.f, 0.f, 0.f, 0.f};

    const int sc = tid >> 2;
    const int sk = (tid & 3) * 8;

    for (int k0 = 0; k0 < CIN; k0 += 32) {
        #pragma unroll
        for (int j = 0; j < 8; ++j)
            Bs[sc][sk + j] = f2bf(W1[(size_t)(k0 + sk + j) * HDIM + bn + sc]);
        __syncthreads();

        bf16x8 af[2];
        #pragma unroll
        for (int mt = 0; mt < 2; ++mt) {
            const float* xp = x + (size_t)(bm + w * 32 + mt * 16 + lr) * CIN + k0 + lg * 8;
            float4 h0 = *reinterpret_cast<const float4*>(xp);
            float4 h1 = *reinterpret_cast<const float4*>(xp + 4);
            af[mt][0] = (short)f2bf(h0.x); af[mt][1] = (short)f2bf(h0.y);
            af[mt][2] = (short)f2bf(h0.z); af[mt][3] = (short)f2bf(h0.w);
            af[mt][4] = (short)f2bf(h1.x); af[mt][5] = (short)f2bf(h1.y);
            af[mt][6] = (short)f2bf(h1.z); af[mt][7] = (short)f2bf(h1.w);
        }
        #pragma unroll
        for (int nt = 0; nt < 4; ++nt) {
            bf16x8 bf = *reinterpret_cast<const bf16x8*>(&Bs[nt * 16 + lr][lg * 8]);
            #pragma unroll
            for (int mt = 0; mt < 2; ++mt)
                acc[mt][nt] = __builtin_amdgcn_mfma_f32_16x16x32_bf16(
                    af[mt], bf, acc[mt][nt], 0, 0, 0);
        }
        __syncthreads();
    }

    #pragma unroll
    for (int nt = 0; nt < 4; ++nt) {
        const int col = bn + nt * 16 + lr;
        #pragma unroll
        for (int mt = 0; mt < 2; ++mt)
            #pragma unroll
            for (int i = 0; i < 4; ++i) {
                const int row = bm + w * 32 + mt * 16 + lg * 4 + i;
                Z[(size_t)row * HDIM + col] = acc[mt][nt][i];
            }
    }
}

// ---------------------------------------------------------------------------
// Kernel 5 (MFMA): S = bf16(x_skip) @ bf16(W1[256:,:]); epilogue fuses the
// knn interpolation: H = relu(S + sum_k w_k Z[i_k] + b1), H stored bf16.
// Gather indices clamped (defensive: bugs -> absmax, not fault).
// ---------------------------------------------------------------------------
__global__ __launch_bounds__(256) void gemm_SH(
    const float* __restrict__ x_skip, const float* __restrict__ W1,
    const float* __restrict__ b1, const float* __restrict__ Z,
    const float4* __restrict__ nbrw, const uint4* __restrict__ nbri,
    u16* __restrict__ H)
{
    __shared__ alignas(16) u16 Bs[64][40];
    const int tid = threadIdx.x;
    const int w = tid >> 6, l = tid & 63;
    const int bm = blockIdx.x * 128;
    const int bn = blockIdx.y * 64;
    const int lr = l & 15, lg = l >> 4;

    f32x4 acc[2][4];
    #pragma unroll
    for (int mt = 0; mt < 2; ++mt)
        #pragma unroll
        for (int nt = 0; nt < 4; ++nt)
            acc[mt][nt] = (f32x4){0.f, 0.f, 0.f, 0.f};

    const int sc = tid >> 2;
    const int sk = (tid & 3) * 8;

    for (int k0 = 0; k0 < CSK; k0 += 32) {
        #pragma unroll
        for (int j = 0; j < 8; ++j)
            Bs[sc][sk + j] = f2bf(W1[(size_t)(CIN + k0 + sk + j) * HDIM + bn + sc]);
        __syncthreads();

        bf16x8 af[2];
        #pragma unroll
        for (int mt = 0; mt < 2; ++mt) {
            const float* xp = x_skip + (size_t)(bm + w * 32 + mt * 16 + lr) * CSK + k0 + lg * 8;
            float4 h0 = *reinterpret_cast<const float4*>(xp);
            float4 h1 = *reinterpret_cast<const float4*>(xp + 4);
            af[mt][0] = (short)f2bf(h0.x); af[mt][1] = (short)f2bf(h0.y);
            af[mt][2] = (short)f2bf(h0.z); af[mt][3] = (short)f2bf(h0.w);
            af[mt][4] = (short)f2bf(h1.x); af[mt][5] = (short)f2bf(h1.y);
            af[mt][6] = (short)f2bf(h1.z); af[mt][7] = (short)f2bf(h1.w);
        }
        #pragma unroll
        for (int nt = 0; nt < 4; ++nt) {
            bf16x8 bf = *reinterpret_cast<const bf16x8*>(&Bs[nt * 16 + lr][lg * 8]);
            #pragma unroll
            for (int mt = 0; mt < 2; ++mt)
                acc[mt][nt] = __builtin_amdgcn_mfma_f32_16x16x32_bf16(
                    af[mt], bf, acc[mt][nt], 0, 0, 0);
        }
        __syncthreads();
    }

    // epilogue: blend interpolated Z rows + bias + relu -> H (bf16)
    #pragma unroll
    for (int mt = 0; mt < 2; ++mt) {
        #pragma unroll
        for (int i = 0; i < 4; ++i) {
            const int row = bm + w * 32 + mt * 16 + lg * 4 + i;
            const float4 wv = nbrw[row];
            const uint4  iv = nbri[row];
            const float* z0 = Z + (size_t)(iv.x & 4095u) * HDIM;  // clamp: no OOB
            const float* z1 = Z + (size_t)(iv.y & 4095u) * HDIM;
            const float* z2 = Z + (size_t)(iv.z & 4095u) * HDIM;
            #pragma unroll
            for (int nt = 0; nt < 4; ++nt) {
                const int col = bn + nt * 16 + lr;
                float zb = wv.x * z0[col] + wv.y * z1[col] + wv.z * z2[col];
                float v = acc[mt][nt][i] + zb + b1[col];
                H[(size_t)row * HDIM + col] = f2bf(v > 0.f ? v : 0.f);
            }
        }
    }
}

// ---------------------------------------------------------------------------
// Kernel 6 (MFMA): out = H @ W2 + b2.  H bf16 [16384,256], out f32.
// ---------------------------------------------------------------------------
__global__ __launch_bounds__(256) void gemm2_mfma(
    const u16* __restrict__ H, const float* __restrict__ W2,
    const float* __restrict__ b2, float* __restrict__ out)
{
    __shared__ alignas(16) u16 Bs[64][40];
    const int tid = threadIdx.x;
    const int w = tid >> 6, l = tid & 63;
    const int bm = blockIdx.x * 128;
    const int bn = blockIdx.y * 64;
    const int lr = l & 15, lg = l >> 4;

    f32x4 acc[2][4];
    #pragma unroll
    for (int mt = 0; mt < 2; ++mt)
        #pragma unroll
        for (int nt = 0; nt < 4; ++nt)
            acc[mt][nt] = (f32x4){0.f, 0.f, 0.f, 0.f};

    const int sc = tid >> 2;
    const int sk = (tid & 3) * 8;

    for (int k0 = 0; k0 < HDIM; k0 += 32) {
        #pragma unroll
        for (int j = 0; j < 8; ++j)
            Bs[sc][sk + j] = f2bf(W2[(size_t)(k0 + sk + j) * HDIM + bn + sc]);
        __syncthreads();

        bf16x8 af[2];
        #pragma unroll
        for (int mt = 0; mt < 2; ++mt) {
            const int row = bm + w * 32 + mt * 16 + lr;
            af[mt] = *reinterpret_cast<const bf16x8*>(H + (size_t)row * HDIM + k0 + lg * 8);
        }
        #pragma unroll
        for (int nt = 0; nt < 4; ++nt) {
            bf16x8 bf = *reinterpret_cast<const bf16x8*>(&Bs[nt * 16 + lr][lg * 8]);
            #pragma unroll
            for (int mt = 0; mt < 2; ++mt)
                acc[mt][nt] = __builtin_amdgcn_mfma_f32_16x16x32_bf16(
                    af[mt], bf, acc[mt][nt], 0, 0, 0);
        }
        __syncthreads();
    }

    #pragma unroll
    for (int nt = 0; nt < 4; ++nt) {
        const int col = bn + nt * 16 + lr;
        const float bias = b2[col];
        #pragma unroll
        for (int mt = 0; mt < 2; ++mt)
            #pragma unroll
            for (int i = 0; i < 4; ++i) {
                const int row = bm + w * 32 + mt * 16 + lg * 4 + i;
                out[(size_t)row * HDIM + col] = acc[mt][nt][i] + bias;
            }
    }
}

// ---------------------------------------------------------------------------
extern "C" void kernel_launch(void* const* d_in, const int* in_sizes, int n_in,
                              void* d_out, int out_size, void* d_ws, size_t ws_size,
                              hipStream_t stream) {
    const float* x        = (const float*)d_in[0];
    const float* pos      = (const float*)d_in[1];
    const float* x_skip   = (const float*)d_in[2];
    const float* pos_skip = (const float*)d_in[3];
    const float* W1       = (const float*)d_in[4];
    const float* b1       = (const float*)d_in[5];
    const float* W2       = (const float*)d_in[6];
    const float* b2       = (const float*)d_in[7];

    // d_ws (12.5 MiB, proven): Hbuf 8M | Z 4M | nbrw 256K | nbri 256K
    u16*    Hbuf = (u16*)d_ws;                               // [16384][256] bf16
    float*  Z    = (float*)((char*)d_ws + (8u << 20));       // [4096][256] f32
    float4* nbrw = (float4*)((char*)d_ws + (12u << 20));
    uint4*  nbri = (uint4*)((char*)d_ws + (12u << 20) + (256u << 10));

    // d_out scratch (out is 16.78 MB; all scratch dead before gemm2 writes):
    float* candM = (float*)d_out;                            // [32][16384] f32 = 2 MiB
    u32*   shsel = (u32*)((char*)d_out + (3u << 20));        // [16384] u32 = 64 KiB
    float* out   = (float*)d_out;

    knn_scanM       <<<dim3(32, NSHARD), 256, 0, stream>>>(pos, pos_skip, candM);
    knn_maskS       <<<64, 256, 0, stream>>>(candM, shsel);
    knn_rescan_merge<<<256, 256, 0, stream>>>(pos, pos_skip, shsel, nbrw, nbri);
    gemm_Z          <<<dim3(32, 4), 256, 0, stream>>>(x, W1, Z);
    gemm_SH         <<<dim3(128, 4), 256, 0, stream>>>(x_skip, W1, b1, Z, nbrw, nbri, Hbuf);
    gemm2_mfma      <<<dim3(128, 4), 256, 0, stream>>>(Hbuf, W2, b2, out);
}

// Round 16
// 64.072 us; speedup vs baseline: 2.2488x; 1.0982x over previous
//
#include <hip/hip_runtime.h>
#include <hip/hip_bf16.h>

#define N_PTS 4096
#define M_PTS 16384
#define CIN   256
#define CSK   128
#define KDIM  384   // CIN + CSK
#define HDIM  256
#define NSHARD 32
#define SHPTS (N_PTS / NSHARD)   // 128

typedef unsigned int  u32;
typedef unsigned short u16;
typedef __attribute__((ext_vector_type(8))) short bf16x8;
typedef __attribute__((ext_vector_type(4))) float f32x4;

__device__ __forceinline__ u16 f2bf(float f) {
    union { float f; u32 i; } w; w.f = f;
    u32 x = w.i;
    u32 r = x + 0x7fffu + ((x >> 16) & 1u);   // RTNE
    return (u16)(r >> 16);
}

// strict "better" with lower-index tie-break (stable-sort semantics)
__device__ __forceinline__ bool ltk(float s, int p, float t, int i) {
    return (s < t) || (s == t && p < i);
}
__device__ __forceinline__ void ins3(float s, int p,
                                     float& t0, float& t1, float& t2,
                                     int& i0, int& i1, int& i2) {
    if (ltk(s, p, t2, i2)) {
        if (ltk(s, p, t1, i1)) {
            t2 = t1; i2 = i1;
            if (ltk(s, p, t0, i0)) { t1 = t0; i1 = i0; t0 = s; i0 = p; }
            else                   { t1 = s;  i1 = p; }
        } else { t2 = s; i2 = p; }
    }
}

// branchless sorted top-3 insert, strict < (ascending-index stream => stable)
#define INS3BL(s, p, t0, t1, t2, i0, i1, i2)                              \
    {                                                                     \
        float _o0 = t0, _o1 = t1, _o2 = t2;                               \
        int _a0 = i0, _a1 = i1, _a2 = i2;                                 \
        bool _c0 = (s) < _o0, _c1 = (s) < _o1, _c2 = (s) < _o2;           \
        t0 = _c0 ? (s) : _o0;              i0 = _c0 ? (p) : _a0;          \
        t1 = _c0 ? _o0 : (_c1 ? (s) : _o1); i1 = _c0 ? _a0 : (_c1 ? (p) : _a1); \
        t2 = _c1 ? _o1 : (_c2 ? (s) : _o2); i2 = _c1 ? _a1 : (_c2 ? (p) : _a2); \
    }

// branchless top-3 insert: values via min/med3, indices via cmp+sel.
// Proven bit-exact (rounds 9/14/15). Strict <, stable for ascending streams.
#define INS3MM(s, p, t0, t1, t2, i0, i1, i2)                              \
    {                                                                     \
        bool _c0 = (s) < t0, _c1 = (s) < t1, _c2 = (s) < t2;              \
        int _oi0 = i0, _oi1 = i1;                                         \
        i0 = _c0 ? (p) : i0;                                              \
        i1 = _c0 ? _oi0 : (_c1 ? (p) : i1);                               \
        i2 = _c1 ? _oi1 : (_c2 ? (p) : i2);                               \
        float _ot0 = t0, _ot1 = t1;                                       \
        t0 = fminf(t0, (s));                                              \
        t1 = __builtin_amdgcn_fmed3f(_ot0, t1, (s));                      \
        t2 = __builtin_amdgcn_fmed3f(_ot1, t2, (s));                      \
    }

// ---------------------------------------------------------------------------
// Kernel 1 (FAT): blocks 0..511 = min-only sharded scan (4 queries/thread:
// one LDS broadcast feeds 24 VALU ops; halves LDS-pipe traffic vs 2q);
// blocks 512..639 = gemm_Z (independent work, complementary pipes).
// Scan: bit-exact fp32 d^2 = (|q|^2 - 2*fma(qz,pz,fma(qy,py,qx*px))) + |p|^2;
// fminf exact & order-independent -> candM[sh*M+m] = exact shard min.
// ---------------------------------------------------------------------------
__global__ __launch_bounds__(256) void scanM_gemmZ(
    const float* __restrict__ pos,
    const float* __restrict__ pos_skip,
    float* __restrict__ candM,
    const float* __restrict__ x,
    const float* __restrict__ W1,
    float* __restrict__ Z)
{
    const int bid = blockIdx.x;
    const int tid = threadIdx.x;

    if (bid < 512) {
        // ------------------- scanM: 4 queries per thread -------------------
        __shared__ float4 spts[SHPTS];     // 2 KB
        const int bx = bid & 15, sh = bid >> 4;
        const int pbase = sh * SHPTS;

        if (tid < SHPTS) {
            const int i = pbase + tid;
            float px = pos[3 * i], py = pos[3 * i + 1], pz = pos[3 * i + 2];
            float pn = __fadd_rn(__fadd_rn(__fmul_rn(px, px), __fmul_rn(py, py)),
                                 __fmul_rn(pz, pz));
            spts[tid] = make_float4(px, py, pz, pn);
        }

        const int mb = bx * 1024 + tid;    // queries mb, +256, +512, +768
        float qx[4], qy[4], qz[4], qn[4];
        #pragma unroll
        for (int q = 0; q < 4; ++q) {
            const int m = mb + q * 256;
            qx[q] = pos_skip[3 * m];
            qy[q] = pos_skip[3 * m + 1];
            qz[q] = pos_skip[3 * m + 2];
            qn[q] = __fadd_rn(__fadd_rn(__fmul_rn(qx[q], qx[q]), __fmul_rn(qy[q], qy[q])),
                              __fmul_rn(qz[q], qz[q]));
        }
        __syncthreads();

        float e[4] = {3.4e38f, 3.4e38f, 3.4e38f, 3.4e38f};

        #pragma unroll 8
        for (int j = 0; j < SHPTS; ++j) {
            float4 v = spts[j];            // wave-uniform broadcast read
            #pragma unroll
            for (int q = 0; q < 4; ++q) {
                float b = __fmaf_rn(qz[q], v.z, __fmaf_rn(qy[q], v.y, __fmul_rn(qx[q], v.x)));
                float s = __fadd_rn(__fmaf_rn(-2.0f, b, qn[q]), v.w);
                e[q] = fminf(e[q], s);
            }
        }

        #pragma unroll
        for (int q = 0; q < 4; ++q)
            candM[(size_t)sh * M_PTS + mb + q * 256] = e[q];
    } else {
        // ------------------- gemm_Z: Z = bf16(x) @ bf16(W1a) ---------------
        __shared__ alignas(16) u16 Bs[64][40];
        const int id = bid - 512;          // 128 blocks: (id&31)*128 x (id>>5)*64
        const int w = tid >> 6, l = tid & 63;
        const int bm = (id & 31) * 128;
        const int bn = (id >> 5) * 64;
        const int lr = l & 15, lg = l >> 4;

        f32x4 acc[2][4];
        #pragma unroll
        for (int mt = 0; mt < 2; ++mt)
            #pragma unroll
            for (int nt = 0; nt < 4; ++nt)
                acc[mt][nt] = (f32x4){0.f, 0.f, 0.f, 0.f};

        const int sc = tid >> 2;
        const int sk = (tid & 3) * 8;

        for (int k0 = 0; k0 < CIN; k0 += 32) {
            #pragma unroll
            for (int j = 0; j < 8; ++j)
                Bs[sc][sk + j] = f2bf(W1[(size_t)(k0 + sk + j) * HDIM + bn + sc]);
            __syncthreads();

            bf16x8 af[2];
            #pragma unroll
            for (int mt = 0; mt < 2; ++mt) {
                const float* xp = x + (size_t)(bm + w * 32 + mt * 16 + lr) * CIN + k0 + lg * 8;
                float4 h0 = *reinterpret_cast<const float4*>(xp);
                float4 h1 = *reinterpret_cast<const float4*>(xp + 4);
                af[mt][0] = (short)f2bf(h0.x); af[mt][1] = (short)f2bf(h0.y);
                af[mt][2] = (short)f2bf(h0.z); af[mt][3] = (short)f2bf(h0.w);
                af[mt][4] = (short)f2bf(h1.x); af[mt][5] = (short)f2bf(h1.y);
                af[mt][6] = (short)f2bf(h1.z); af[mt][7] = (short)f2bf(h1.w);
            }
            #pragma unroll
            for (int nt = 0; nt < 4; ++nt) {
                bf16x8 bf = *reinterpret_cast<const bf16x8*>(&Bs[nt * 16 + lr][lg * 8]);
                #pragma unroll
                for (int mt = 0; mt < 2; ++mt)
                    acc[mt][nt] = __builtin_amdgcn_mfma_f32_16x16x32_bf16(
                        af[mt], bf, acc[mt][nt], 0, 0, 0);
            }
            __syncthreads();
        }

        #pragma unroll
        for (int nt = 0; nt < 4; ++nt) {
            const int col = bn + nt * 16 + lr;
            #pragma unroll
            for (int mt = 0; mt < 2; ++mt)
                #pragma unroll
                for (int i = 0; i < 4; ++i) {
                    const int row = bm + w * 32 + mt * 16 + lg * 4 + i;
                    Z[(size_t)row * HDIM + col] = acc[mt][nt][i];
                }
        }
    }
}

// ---------------------------------------------------------------------------
// Kernel 2: shard selection + rescan + merge + weights. 4 threads/query.
// Phase A: slot s INS3BL's shards s*8..s*8+7 by (min, sh) (ascending sh +
//   strict < == lexicographic); slot 0 ltk-ins3 merges the 4 partial lists
//   -> exact global 3 smallest (min,sh) keys == old maskS selection.
//   THEOREM (R15-proven): the exact (value,index) top-3 points lie in
//   these 3 shards.
// Phase B: slots 0..2 scan one shard each (proven INS3MM, ascending index);
//   slot 0 ltk-ins3 merges 9 candidates -> exact stable top-3 -> weights.
// ---------------------------------------------------------------------------
__global__ __launch_bounds__(256) void knn_select_rescan(
    const float* __restrict__ pos,
    const float* __restrict__ pos_skip,
    const float* __restrict__ candM,
    float4* __restrict__ nbrw, uint4* __restrict__ nbri)
{
    __shared__ float sv[64][4][3];
    __shared__ int   si[64][4][3];
    __shared__ u32   ssel[64];
    const int tid  = threadIdx.x;
    const int ql   = tid >> 2;
    const int slot = tid & 3;
    const int m = blockIdx.x * 64 + ql;   // 256 blocks * 64 queries

    // Phase A: per-slot partial (min, sh) top-3 over 8 shards
    {
        float t0 = 3.4e38f, t1 = 3.4e38f, t2 = 3.4e38f;
        int   s0 = 63, s1 = 63, s2 = 63;
        #pragma unroll
        for (int k = 0; k < 8; ++k) {
            const int sh = slot * 8 + k;
            float mn = candM[(size_t)sh * M_PTS + m];
            INS3BL(mn, sh, t0, t1, t2, s0, s1, s2);
        }
        sv[ql][slot][0] = t0; sv[ql][slot][1] = t1; sv[ql][slot][2] = t2;
        si[ql][slot][0] = s0; si[ql][slot][1] = s1; si[ql][slot][2] = s2;
    }
    __syncthreads();
    if (slot == 0) {
        float t0 = 3.4e38f, t1 = 3.4e38f, t2 = 3.4e38f;
        int   s0 = 63, s1 = 63, s2 = 63;
        #pragma unroll
        for (int s = 0; s < 4; ++s)
            #pragma unroll
            for (int k = 0; k < 3; ++k)
                ins3(sv[ql][s][k], si[ql][s][k], t0, t1, t2, s0, s1, s2);
        ssel[ql] = (u32)s0 | ((u32)s1 << 8) | ((u32)s2 << 16);
    }
    __syncthreads();
    const u32 sel = ssel[ql];

    // Phase B: rescan the 3 selected shards
    if (slot < 3) {
        const int sh = (sel >> (8 * slot)) & 63;
        const int pb = sh * SHPTS;

        const float qx = pos_skip[3 * m];
        const float qy = pos_skip[3 * m + 1];
        const float qz = pos_skip[3 * m + 2];
        const float qn = __fadd_rn(__fadd_rn(__fmul_rn(qx, qx), __fmul_rn(qy, qy)),
                                   __fmul_rn(qz, qz));

        float t0 = 3.4e38f, t1 = 3.4e38f, t2 = 3.4e38f;
        int   i0 = 0x7fffffff, i1 = 0x7fffffff, i2 = 0x7fffffff;

        #pragma unroll 4
        for (int j = 0; j < SHPTS; ++j) {
            const int p = pb + j;
            float px = pos[3 * p], py = pos[3 * p + 1], pz = pos[3 * p + 2];
            float pn = __fadd_rn(__fadd_rn(__fmul_rn(px, px), __fmul_rn(py, py)),
                                 __fmul_rn(pz, pz));
            float b = __fmaf_rn(qz, pz, __fmaf_rn(qy, py, __fmul_rn(qx, px)));
            float s = __fadd_rn(__fmaf_rn(-2.0f, b, qn), pn);
            INS3MM(s, p, t0, t1, t2, i0, i1, i2);
        }
        sv[ql][slot][0] = t0; sv[ql][slot][1] = t1; sv[ql][slot][2] = t2;
        si[ql][slot][0] = i0; si[ql][slot][1] = i1; si[ql][slot][2] = i2;
    }
    __syncthreads();

    if (slot == 0) {
        float t0 = 3.4e38f, t1 = 3.4e38f, t2 = 3.4e38f;
        int   i0 = 0x7fffffff, i1 = 0x7fffffff, i2 = 0x7fffffff;
        #pragma unroll
        for (int s = 0; s < 3; ++s)
            #pragma unroll
            for (int k = 0; k < 3; ++k)
                ins3(sv[ql][s][k], si[ql][s][k], t0, t1, t2, i0, i1, i2);

        // inverse-distance weights (reference clamps d^2 at 1e-16), fp32
        float w0 = __fdiv_rn(1.0f, fmaxf(t0, 1e-16f));
        float w1 = __fdiv_rn(1.0f, fmaxf(t1, 1e-16f));
        float w2 = __fdiv_rn(1.0f, fmaxf(t2, 1e-16f));
        float inv = __fdiv_rn(1.0f, __fadd_rn(__fadd_rn(w0, w1), w2));
        nbrw[m] = make_float4(w0 * inv, w1 * inv, w2 * inv, 0.f);
        nbri[m] = make_uint4((u32)i0, (u32)i1, (u32)i2, 0u);
    }
}

// ---------------------------------------------------------------------------
// Kernel 3 (MFMA): S = bf16(x_skip) @ bf16(W1[256:,:]); epilogue fuses the
// knn interpolation: H = relu(S + sum_k w_k Z[i_k] + b1), H stored bf16.
// Gather indices clamped (defensive: bugs -> absmax, not fault).
// ---------------------------------------------------------------------------
__global__ __launch_bounds__(256) void gemm_SH(
    const float* __restrict__ x_skip, const float* __restrict__ W1,
    const float* __restrict__ b1, const float* __restrict__ Z,
    const float4* __restrict__ nbrw, const uint4* __restrict__ nbri,
    u16* __restrict__ H)
{
    __shared__ alignas(16) u16 Bs[64][40];
    const int tid = threadIdx.x;
    const int w = tid >> 6, l = tid & 63;
    const int bm = blockIdx.x * 128;
    const int bn = blockIdx.y * 64;
    const int lr = l & 15, lg = l >> 4;

    f32x4 acc[2][4];
    #pragma unroll
    for (int mt = 0; mt < 2; ++mt)
        #pragma unroll
        for (int nt = 0; nt < 4; ++nt)
            acc[mt][nt] = (f32x4){0.f, 0.f, 0.f, 0.f};

    const int sc = tid >> 2;
    const int sk = (tid & 3) * 8;

    for (int k0 = 0; k0 < CSK; k0 += 32) {
        #pragma unroll
        for (int j = 0; j < 8; ++j)
            Bs[sc][sk + j] = f2bf(W1[(size_t)(CIN + k0 + sk + j) * HDIM + bn + sc]);
        __syncthreads();

        bf16x8 af[2];
        #pragma unroll
        for (int mt = 0; mt < 2; ++mt) {
            const float* xp = x_skip + (size_t)(bm + w * 32 + mt * 16 + lr) * CSK + k0 + lg * 8;
            float4 h0 = *reinterpret_cast<const float4*>(xp);
            float4 h1 = *reinterpret_cast<const float4*>(xp + 4);
            af[mt][0] = (short)f2bf(h0.x); af[mt][1] = (short)f2bf(h0.y);
            af[mt][2] = (short)f2bf(h0.z); af[mt][3] = (short)f2bf(h0.w);
            af[mt][4] = (short)f2bf(h1.x); af[mt][5] = (short)f2bf(h1.y);
            af[mt][6] = (short)f2bf(h1.z); af[mt][7] = (short)f2bf(h1.w);
        }
        #pragma unroll
        for (int nt = 0; nt < 4; ++nt) {
            bf16x8 bf = *reinterpret_cast<const bf16x8*>(&Bs[nt * 16 + lr][lg * 8]);
            #pragma unroll
            for (int mt = 0; mt < 2; ++mt)
                acc[mt][nt] = __builtin_amdgcn_mfma_f32_16x16x32_bf16(
                    af[mt], bf, acc[mt][nt], 0, 0, 0);
        }
        __syncthreads();
    }

    // epilogue: blend interpolated Z rows + bias + relu -> H (bf16)
    #pragma unroll
    for (int mt = 0; mt < 2; ++mt) {
        #pragma unroll
        for (int i = 0; i < 4; ++i) {
            const int row = bm + w * 32 + mt * 16 + lg * 4 + i;
            const float4 wv = nbrw[row];
            const uint4  iv = nbri[row];
            const float* z0 = Z + (size_t)(iv.x & 4095u) * HDIM;  // clamp: no OOB
            const float* z1 = Z + (size_t)(iv.y & 4095u) * HDIM;
            const float* z2 = Z + (size_t)(iv.z & 4095u) * HDIM;
            #pragma unroll
            for (int nt = 0; nt < 4; ++nt) {
                const int col = bn + nt * 16 + lr;
                float zb = wv.x * z0[col] + wv.y * z1[col] + wv.z * z2[col];
                float v = acc[mt][nt][i] + zb + b1[col];
                H[(size_t)row * HDIM + col] = f2bf(v > 0.f ? v : 0.f);
            }
        }
    }
}

// ---------------------------------------------------------------------------
// Kernel 4 (MFMA): out = H @ W2 + b2.  H bf16 [16384,256], out f32.
// ---------------------------------------------------------------------------
__global__ __launch_bounds__(256) void gemm2_mfma(
    const u16* __restrict__ H, const float* __restrict__ W2,
    const float* __restrict__ b2, float* __restrict__ out)
{
    __shared__ alignas(16) u16 Bs[64][40];
    const int tid = threadIdx.x;
    const int w = tid >> 6, l = tid & 63;
    const int bm = blockIdx.x * 128;
    const int bn = blockIdx.y * 64;
    const int lr = l & 15, lg = l >> 4;

    f32x4 acc[2][4];
    #pragma unroll
    for (int mt = 0; mt < 2; ++mt)
        #pragma unroll
        for (int nt = 0; nt < 4; ++nt)
            acc[mt][nt] = (f32x4){0.f, 0.f, 0.f, 0.f};

    const int sc = tid >> 2;
    const int sk = (tid & 3) * 8;

    for (int k0 = 0; k0 < HDIM; k0 += 32) {
        #pragma unroll
        for (int j = 0; j < 8; ++j)
            Bs[sc][sk + j] = f2bf(W2[(size_t)(k0 + sk + j) * HDIM + bn + sc]);
        __syncthreads();

        bf16x8 af[2];
        #pragma unroll
        for (int mt = 0; mt < 2; ++mt) {
            const int row = bm + w * 32 + mt * 16 + lr;
            af[mt] = *reinterpret_cast<const bf16x8*>(H + (size_t)row * HDIM + k0 + lg * 8);
        }
        #pragma unroll
        for (int nt = 0; nt < 4; ++nt) {
            bf16x8 bf = *reinterpret_cast<const bf16x8*>(&Bs[nt * 16 + lr][lg * 8]);
            #pragma unroll
            for (int mt = 0; mt < 2; ++mt)
                acc[mt][nt] = __builtin_amdgcn_mfma_f32_16x16x32_bf16(
                    af[mt], bf, acc[mt][nt], 0, 0, 0);
        }
        __syncthreads();
    }

    #pragma unroll
    for (int nt = 0; nt < 4; ++nt) {
        const int col = bn + nt * 16 + lr;
        const float bias = b2[col];
        #pragma unroll
        for (int mt = 0; mt < 2; ++mt)
            #pragma unroll
            for (int i = 0; i < 4; ++i) {
                const int row = bm + w * 32 + mt * 16 + lg * 4 + i;
                out[(size_t)row * HDIM + col] = acc[mt][nt][i] + bias;
            }
    }
}

// ---------------------------------------------------------------------------
extern "C" void kernel_launch(void* const* d_in, const int* in_sizes, int n_in,
                              void* d_out, int out_size, void* d_ws, size_t ws_size,
                              hipStream_t stream) {
    const float* x        = (const float*)d_in[0];
    const float* pos      = (const float*)d_in[1];
    const float* x_skip   = (const float*)d_in[2];
    const float* pos_skip = (const float*)d_in[3];
    const float* W1       = (const float*)d_in[4];
    const float* b1       = (const float*)d_in[5];
    const float* W2       = (const float*)d_in[6];
    const float* b2       = (const float*)d_in[7];

    // d_ws (12.5 MiB, proven): Hbuf 8M | Z 4M | nbrw 256K | nbri 256K
    u16*    Hbuf = (u16*)d_ws;                               // [16384][256] bf16
    float*  Z    = (float*)((char*)d_ws + (8u << 20));       // [4096][256] f32
    float4* nbrw = (float4*)((char*)d_ws + (12u << 20));
    uint4*  nbri = (uint4*)((char*)d_ws + (12u << 20) + (256u << 10));

    // d_out scratch (dead before gemm2 writes out):
    float* candM = (float*)d_out;                            // [32][16384] f32 = 2 MiB
    float* out   = (float*)d_out;

    scanM_gemmZ      <<<640, 256, 0, stream>>>(pos, pos_skip, candM, x, W1, Z);
    knn_select_rescan<<<256, 256, 0, stream>>>(pos, pos_skip, candM, nbrw, nbri);
    gemm_SH          <<<dim3(128, 4), 256, 0, stream>>>(x_skip, W1, b1, Z, nbrw, nbri, Hbuf);
    gemm2_mfma       <<<dim3(128, 4), 256, 0, stream>>>(Hbuf, W2, b2, out);
}